// Round 1
// baseline (1476.230 us; speedup 1.0000x reference)
//
#include <hip/hip_runtime.h>

#define N_TOK 4096
#define D_DIM 2048
#define F_DIM 16384
#define K_WIN 32
#define CAP   768
#define TOPC  48
#define THRESH 2.0f

typedef short s8v __attribute__((ext_vector_type(8)));
typedef float f4v __attribute__((ext_vector_type(4)));

__device__ __forceinline__ unsigned short f2bf(float f) {
  unsigned int u = __float_as_uint(f);
  u = (u + 0x7fffu + ((u >> 16) & 1u)) >> 16;
  return (unsigned short)u;
}

// fp32 -> bf16 (round-nearest-even), vectorized
__global__ __launch_bounds__(256) void cvt_bf16_kernel(const float* __restrict__ src,
                                                       unsigned short* __restrict__ dst,
                                                       int n4) {
  int i = blockIdx.x * blockDim.x + threadIdx.x;
  int stride = gridDim.x * blockDim.x;
  for (; i < n4; i += stride) {
    float4 v = ((const float4*)src)[i];
    ushort4 o;
    o.x = f2bf(v.x); o.y = f2bf(v.y); o.z = f2bf(v.z); o.w = f2bf(v.w);
    ((ushort4*)dst)[i] = o;
  }
}

__device__ __forceinline__ void load_lds16(const unsigned short* g, unsigned short* l) {
  __builtin_amdgcn_global_load_lds(
      (const __attribute__((address_space(1))) unsigned int*)g,
      (__attribute__((address_space(3))) unsigned int*)l, 16, 0, 0);
}

// C[m,n] = sum_k A[m,k]*B[n,k]  (both row-major bf16, K=2048)
// 128x128 tile, 4 waves (2x2), 16x16x32 bf16 MFMA, global_load_lds staging.
// Epilogue: scatter (score, col) for score > THRESH into per-row candidate lists.
__global__ __launch_bounds__(256) void gemm_cand(const unsigned short* __restrict__ A,
                                                 const unsigned short* __restrict__ B,
                                                 int* __restrict__ cnt,
                                                 float* __restrict__ candS,
                                                 int* __restrict__ candI) {
  __shared__ unsigned short As[128 * 32];  // 8KB
  __shared__ unsigned short Bs[128 * 32];  // 8KB
  const int tid = threadIdx.x;
  const int lane = tid & 63;
  const int wave = tid >> 6;
  const int wm = wave >> 1, wn = wave & 1;
  const int m0 = blockIdx.y * 128;
  const int n0 = blockIdx.x * 128;

  f4v acc[4][4];
#pragma unroll
  for (int i = 0; i < 4; i++)
#pragma unroll
    for (int j = 0; j < 4; j++) acc[i][j] = (f4v)0.0f;

  // staging geometry: tile 8192B = 8 chunks of 1KB; wave w takes chunks w and w+4
  const int off0 = wave * 1024 + lane * 16;        // bytes within tile
  const int off1 = (4 + wave) * 1024 + lane * 16;
  const int r0 = off0 >> 6, c0 = (off0 & 63) >> 1; // row, ushort-col within tile
  const int r1 = off1 >> 6, c1 = (off1 & 63) >> 1;

  for (int kt = 0; kt < D_DIM; kt += 32) {
    // stage A (x) and B (W) tiles
    load_lds16(A + (size_t)(m0 + r0) * D_DIM + kt + c0, As + (wave << 9));
    load_lds16(A + (size_t)(m0 + r1) * D_DIM + kt + c1, As + ((4 + wave) << 9));
    load_lds16(B + (size_t)(n0 + r0) * D_DIM + kt + c0, Bs + (wave << 9));
    load_lds16(B + (size_t)(n0 + r1) * D_DIM + kt + c1, Bs + ((4 + wave) << 9));
    __syncthreads();

    s8v a[4], b[4];
#pragma unroll
    for (int mi = 0; mi < 4; mi++)
      a[mi] = *(const s8v*)&As[(wm * 64 + mi * 16 + (lane & 15)) * 32 + (lane >> 4) * 8];
#pragma unroll
    for (int ni = 0; ni < 4; ni++)
      b[ni] = *(const s8v*)&Bs[(wn * 64 + ni * 16 + (lane & 15)) * 32 + (lane >> 4) * 8];
#pragma unroll
    for (int mi = 0; mi < 4; mi++)
#pragma unroll
      for (int ni = 0; ni < 4; ni++)
        acc[mi][ni] = __builtin_amdgcn_mfma_f32_16x16x32_bf16(a[mi], b[ni], acc[mi][ni], 0, 0, 0);
    __syncthreads();
  }

  // epilogue: candidate scatter. C/D layout: col=lane&15, row=(lane>>4)*4+r
#pragma unroll
  for (int mi = 0; mi < 4; mi++) {
    const int rowb = m0 + wm * 64 + mi * 16 + ((lane >> 4) << 2);
#pragma unroll
    for (int ni = 0; ni < 4; ni++) {
      const int col = n0 + wn * 64 + ni * 16 + (lane & 15);
#pragma unroll
      for (int r = 0; r < 4; r++) {
        float s = acc[mi][ni][r];
        if (s > THRESH) {
          int rr = rowb + r;
          int pos = atomicAdd(&cnt[rr], 1);
          if (pos < CAP) {
            candS[(size_t)rr * CAP + pos] = s;
            candI[(size_t)rr * CAP + pos] = col;
          }
        }
      }
    }
  }
}

// one block per row: approx top-48 -> fp64 rescore -> exact top-32 ->
// acts scatter, recon row, per-row loss
__global__ __launch_bounds__(256) void select_rescore(const float* __restrict__ x,
                                                      const float* __restrict__ W,
                                                      const float* __restrict__ candS,
                                                      const int* __restrict__ candI,
                                                      const int* __restrict__ cnt,
                                                      float* __restrict__ acts,
                                                      float* __restrict__ recon,
                                                      double* __restrict__ rowloss) {
  const int row = blockIdx.x;
  const int tid = threadIdx.x;
  const int lane = tid & 63;
  const int wave = tid >> 6;

  __shared__ float sS[CAP];
  __shared__ int sI[CAP];
  __shared__ int sel[TOPC];
  __shared__ double sx[TOPC];
  __shared__ float rmax[4];
  __shared__ int rpos[4];
  __shared__ double rsum[4];
  __shared__ int wIdx[K_WIN];
  __shared__ double wVal[K_WIN];

  int n = cnt[row];
  if (n > CAP) n = CAP;
  for (int i = tid; i < n; i += 256) {
    sS[i] = candS[(size_t)row * CAP + i];
    sI[i] = candI[(size_t)row * CAP + i];
  }
  __syncthreads();

  // approx top-48 by repeated argmax (bf16-GEMM scores; 50-sigma margin vs rank-32)
  for (int it = 0; it < TOPC; ++it) {
    float best = -1e30f;
    int bp = -1;
    for (int i = tid; i < n; i += 256) {
      float v = sS[i];
      if (v > best) { best = v; bp = i; }
    }
    for (int o = 32; o > 0; o >>= 1) {
      float ov = __shfl_down(best, o);
      int op = __shfl_down(bp, o);
      if (ov > best) { best = ov; bp = op; }
    }
    if (lane == 0) { rmax[wave] = best; rpos[wave] = bp; }
    __syncthreads();
    if (tid == 0) {
      float b = rmax[0]; int p = rpos[0];
      for (int w2 = 1; w2 < 4; w2++)
        if (rmax[w2] > b) { b = rmax[w2]; p = rpos[w2]; }
      sel[it] = (p >= 0) ? sI[p] : 0;
      if (p >= 0) sS[p] = -1e30f;
    }
    __syncthreads();
  }

  // exact fp64 rescore of 48 candidates, wave-parallel
  {
    const float* xp = x + (size_t)row * D_DIM;
    for (int c = wave; c < TOPC; c += 4) {
      const float* wp = W + (size_t)sel[c] * D_DIM;
      double a0 = 0, a1 = 0, a2 = 0, a3 = 0;
      for (int j = lane; j < D_DIM; j += 256) {
        a0 += (double)xp[j] * (double)wp[j];
        a1 += (double)xp[j + 64] * (double)wp[j + 64];
        a2 += (double)xp[j + 128] * (double)wp[j + 128];
        a3 += (double)xp[j + 192] * (double)wp[j + 192];
      }
      double s = (a0 + a1) + (a2 + a3);
      for (int o = 32; o > 0; o >>= 1) s += __shfl_down(s, o);
      if (lane == 0) sx[c] = s;
    }
  }
  __syncthreads();

  // exact top-32 among 48 (serial, deterministic)
  if (tid == 0) {
    for (int it = 0; it < K_WIN; ++it) {
      double b = -1e300; int p = 0;
      for (int c = 0; c < TOPC; c++)
        if (sx[c] > b) { b = sx[c]; p = c; }
      wIdx[it] = sel[p];
      wVal[it] = b;
      sx[p] = -1e300;
    }
  }
  __syncthreads();

  if (tid < K_WIN) acts[(size_t)row * F_DIM + wIdx[tid]] = (float)wVal[tid];

  // recon + loss: thread t owns dims {t, t+256, ..., t+1792}
  double racc[8];
#pragma unroll
  for (int q = 0; q < 8; q++) racc[q] = 0.0;
  for (int i = 0; i < K_WIN; i++) {
    const double v = wVal[i];
    const float* wp = W + (size_t)wIdx[i] * D_DIM;
#pragma unroll
    for (int q = 0; q < 8; q++) racc[q] += v * (double)wp[tid + q * 256];
  }
  const float* xp = x + (size_t)row * D_DIM;
  double ls = 0;
#pragma unroll
  for (int q = 0; q < 8; q++) {
    const int d = tid + q * 256;
    double r = racc[q];
    recon[(size_t)row * D_DIM + d] = (float)r;
    double df = r - (double)xp[d];
    ls += df * df;
  }
  for (int o = 32; o > 0; o >>= 1) ls += __shfl_down(ls, o);
  if (lane == 0) rsum[wave] = ls;
  __syncthreads();
  if (tid == 0) rowloss[row] = rsum[0] + rsum[1] + rsum[2] + rsum[3];
}

__global__ __launch_bounds__(256) void finalize_loss(const double* __restrict__ rowloss,
                                                     float* __restrict__ out) {
  __shared__ double rs[4];
  const int tid = threadIdx.x, lane = tid & 63, wave = tid >> 6;
  double s = 0;
  for (int i = tid; i < N_TOK; i += 256) s += rowloss[i];
  for (int o = 32; o > 0; o >>= 1) s += __shfl_down(s, o);
  if (lane == 0) rs[wave] = s;
  __syncthreads();
  if (tid == 0) out[0] = (float)((rs[0] + rs[1] + rs[2] + rs[3]) / (double)N_TOK);
}

extern "C" void kernel_launch(void* const* d_in, const int* in_sizes, int n_in,
                              void* d_out, int out_size, void* d_ws, size_t ws_size,
                              hipStream_t stream) {
  const float* x = (const float*)d_in[0];  // [4096, 2048]
  const float* W = (const float*)d_in[1];  // [16384, 2048]

  float* out = (float*)d_out;
  float* recon = out + 1;
  float* acts = out + 1 + (size_t)N_TOK * D_DIM;

  // workspace layout (~109 MB)
  char* ws = (char*)d_ws;
  unsigned short* xh = (unsigned short*)ws;                      // 16 MB
  unsigned short* wh = (unsigned short*)(ws + 16777216);         // 64 MB
  float* candS = (float*)(ws + 83886080);                        // 12 MB
  int* candI = (int*)(ws + 96468992);                            // 12 MB
  int* ccnt = (int*)(ws + 109051904);                            // 16 KB
  double* rloss = (double*)(ws + 109068288);                     // 32 KB

  hipMemsetAsync(acts, 0, (size_t)N_TOK * F_DIM * sizeof(float), stream);
  hipMemsetAsync(ccnt, 0, N_TOK * sizeof(int), stream);

  cvt_bf16_kernel<<<2048, 256, 0, stream>>>(x, xh, (N_TOK * D_DIM) / 4);
  cvt_bf16_kernel<<<4096, 256, 0, stream>>>(W, wh, (F_DIM * D_DIM) / 4);

  dim3 ggrid(F_DIM / 128, N_TOK / 128);
  gemm_cand<<<ggrid, 256, 0, stream>>>(xh, wh, ccnt, candS, candI);

  select_rescore<<<N_TOK, 256, 0, stream>>>(x, W, candS, candI, ccnt, acts, recon, rloss);
  finalize_loss<<<1, 256, 0, stream>>>(rloss, out);
}